// Round 11
// baseline (154.900 us; speedup 1.0000x reference)
//
#include <hip/hip_runtime.h>
#include <math.h>

#define NACC 17
#define ACC_STRIDE 32   // pad each f32 accumulator to its own 128B cache line
// acc layout: 0 cnt, 1 sw, 2-4 swx, 5-7 swy, 8-16 swyx[o*3+i]
// Unweighted sums (sx/sy/syx) are NOT tracked in the hot loop: they matter
// only when nep = (count_nonzero < 3), which the last block detects and
// handles by re-reading the input on a cold path (never taken for
// non-degenerate inputs). This frees 15 VGPRs so the compiler can hold a
// deeper global-load batch in flight (r9: 32 accs capped batches at ~4
// loads -> 2.5 TB/s latency-bound).

typedef float f4 __attribute__((ext_vector_type(4)));

// Fence-free fused reduce+finalize (r8/r9: verified, 146.6us total).
//  - NO __threadfence (r4/r6: per-block wbl2 costs ~170us).
//  - Cross-block data via device-scope atomics only.
//  - Plain compiler-scheduled loads (r4: volatile asm kills pipelining).
//  - No cooperative launch (r5: never runs under graph capture).
// (r10 was an infra failure — this is the r10 kernel resubmitted unchanged.)

__device__ __forceinline__ void accum_point(float w, float x0, float x1, float x2,
                                            float y0, float y1, float y2, float* a) {
    a[0] += (w > 0.0f) ? 1.0f : 0.0f;
    a[1] += w;
    a[2] = fmaf(w, x0, a[2]); a[3] = fmaf(w, x1, a[3]); a[4] = fmaf(w, x2, a[4]);
    float wy0 = w * y0, wy1 = w * y1, wy2 = w * y2;
    a[5] += wy0; a[6] += wy1; a[7] += wy2;
    a[8]  = fmaf(wy0, x0, a[8]);  a[9]  = fmaf(wy0, x1, a[9]);  a[10] = fmaf(wy0, x2, a[10]);
    a[11] = fmaf(wy1, x0, a[11]); a[12] = fmaf(wy1, x1, a[12]); a[13] = fmaf(wy1, x2, a[13]);
    a[14] = fmaf(wy2, x0, a[14]); a[15] = fmaf(wy2, x1, a[15]); a[16] = fmaf(wy2, x2, a[16]);
}

__device__ __forceinline__ double det3(const double m[3][3]) {
    return m[0][0] * (m[1][1] * m[2][2] - m[1][2] * m[2][1])
         - m[0][1] * (m[1][0] * m[2][2] - m[1][2] * m[2][0])
         + m[0][2] * (m[1][0] * m[2][1] - m[1][1] * m[2][0]);
}

__global__ __launch_bounds__(256, 1) void kabsch_fused(
    const float* __restrict__ c0, const float* __restrict__ c1,
    const float* __restrict__ w, int N, float* __restrict__ acc32, int nblocks,
    unsigned* __restrict__ ticket, float* __restrict__ out) {
    __shared__ float wred[4][NACC];

    float a[NACC];
    #pragma unroll
    for (int i = 0; i < NACC; ++i) a[i] = 0.0f;

    const int t = threadIdx.x;
    const int lane = t & 63, wave = t >> 6;
    const f4* __restrict__ A4 = (const f4*)c0;
    const f4* __restrict__ B4 = (const f4*)c1;
    const f4* __restrict__ W4 = (const f4*)w;

    // ---- hot loop: 2 groups (8 points) per iteration = 14 independent
    // dwordx4 loads per batch. Boundary dup-group neutralized via w=0
    // (zero weight contributes nothing to any of the 17 sums). ----
    const int ngrp = N >> 2;
    const int stride = gridDim.x << 9;   // gridDim.x * 512
    for (int g0 = (blockIdx.x << 9) + t; g0 < ngrp; g0 += stride) {
        int g1 = g0 + 256;
        bool h1 = g1 < ngrp;
        int g1c = h1 ? g1 : g0;
        const f4* pa0 = A4 + 3 * (size_t)g0;
        const f4* pb0 = B4 + 3 * (size_t)g0;
        const f4* pa1 = A4 + 3 * (size_t)g1c;
        const f4* pb1 = B4 + 3 * (size_t)g1c;
        f4 xa0 = pa0[0], xa1 = pa0[1], xa2 = pa0[2];
        f4 xb0 = pb0[0], xb1 = pb0[1], xb2 = pb0[2];
        f4 xw  = W4[g0];
        f4 ya0 = pa1[0], ya1 = pa1[1], ya2 = pa1[2];
        f4 yb0 = pb1[0], yb1 = pb1[1], yb2 = pb1[2];
        f4 yw  = W4[g1c];
        if (!h1) { yw.x = 0.0f; yw.y = 0.0f; yw.z = 0.0f; yw.w = 0.0f; }
        accum_point(xw.x, xa0.x, xa0.y, xa0.z, xb0.x, xb0.y, xb0.z, a);
        accum_point(xw.y, xa0.w, xa1.x, xa1.y, xb0.w, xb1.x, xb1.y, a);
        accum_point(xw.z, xa1.z, xa1.w, xa2.x, xb1.z, xb1.w, xb2.x, a);
        accum_point(xw.w, xa2.y, xa2.z, xa2.w, xb2.y, xb2.z, xb2.w, a);
        accum_point(yw.x, ya0.x, ya0.y, ya0.z, yb0.x, yb0.y, yb0.z, a);
        accum_point(yw.y, ya0.w, ya1.x, ya1.y, yb0.w, yb1.x, yb1.y, a);
        accum_point(yw.z, ya1.z, ya1.w, ya2.x, yb1.z, yb1.w, yb2.x, a);
        accum_point(yw.w, ya2.y, ya2.z, ya2.w, yb2.y, yb2.z, yb2.w, a);
    }
    // tail points (N % 4) — never taken for N = 4M, correctness-general
    if (blockIdx.x == 0 && t == 0) {
        for (int i = (N >> 2) << 2; i < N; ++i)
            accum_point(w[i], c0[3*i], c0[3*i+1], c0[3*i+2],
                        c1[3*i], c1[3*i+1], c1[3*i+2], a);
    }

    // ---- wave reduction: 17 accs x 6 shuffle stages ----
    #pragma unroll
    for (int i = 0; i < NACC; ++i) {
        float v = a[i];
        v += __shfl_xor(v, 1, 64);
        v += __shfl_xor(v, 2, 64);
        v += __shfl_xor(v, 4, 64);
        v += __shfl_xor(v, 8, 64);
        v += __shfl_xor(v, 16, 64);
        v += __shfl_xor(v, 32, 64);
        a[i] = v;
    }
    if (lane == 0) {
        #pragma unroll
        for (int i = 0; i < NACC; ++i) wred[wave][i] = a[i];
    }
    __syncthreads();

    // ---- publish via native device-scope f32 atomic add (no fence);
    // one accumulator per 128B line ----
    if (t < NACC) {
        float val = wred[0][t] + wred[1][t] + wred[2][t] + wred[3][t];
        float* p = acc32 + (t << 5);   // t * ACC_STRIDE
        asm volatile("global_atomic_add_f32 %0, %1, off"
                     :: "v"(p), "v"(val) : "memory");
    }
    asm volatile("s_waitcnt vmcnt(0)" ::: "memory");  // fadds performed
    __syncthreads();
    __shared__ unsigned amlast;
    if (t == 0) amlast = atomicAdd(ticket, 1u);       // relaxed, coherent
    __syncthreads();
    if (amlast != (unsigned)(nblocks - 1)) return;

    // ---- last-arriving block: read totals via atomic fadd(0, sc0) ----
    __shared__ float tot[NACC];
    if (t < NACC) {
        float* p = acc32 + (t << 5);
        float zero = 0.0f, old;
        asm volatile("global_atomic_add_f32 %0, %1, %2, off sc0"
                     : "=&v"(old) : "v"(p), "v"(zero) : "memory");
        asm volatile("s_waitcnt vmcnt(0)" ::: "memory");
        tot[t] = old;
    }
    __syncthreads();

    // ---- nep cold path: recompute unweighted sums by re-reading input.
    // Uniform branch (all threads read tot[0]); never taken unless
    // count_nonzero < 3. ----
    bool nep = (tot[0] < 3.0f);
    __shared__ double csm[4][15];
    if (nep) {
        double cs[15];
        #pragma unroll
        for (int k = 0; k < 15; ++k) cs[k] = 0.0;
        for (int i = t; i < N; i += 256) {
            double x0 = c0[3*i], x1 = c0[3*i+1], x2 = c0[3*i+2];
            double y0 = c1[3*i], y1 = c1[3*i+1], y2 = c1[3*i+2];
            cs[0] += x0; cs[1] += x1; cs[2] += x2;
            cs[3] += y0; cs[4] += y1; cs[5] += y2;
            cs[6]  += y0*x0; cs[7]  += y0*x1; cs[8]  += y0*x2;
            cs[9]  += y1*x0; cs[10] += y1*x1; cs[11] += y1*x2;
            cs[12] += y2*x0; cs[13] += y2*x1; cs[14] += y2*x2;
        }
        #pragma unroll
        for (int off = 32; off > 0; off >>= 1) {
            #pragma unroll
            for (int k = 0; k < 15; ++k) cs[k] += __shfl_down(cs[k], off, 64);
        }
        if (lane == 0) {
            #pragma unroll
            for (int k = 0; k < 15; ++k) csm[wave][k] = cs[k];
        }
        __syncthreads();
    }
    if (t != 0) return;

    double d[NACC];
    #pragma unroll
    for (int i = 0; i < NACC; ++i) d[i] = (double)tot[i];

    const double EPSF = (double)1.1920929e-7f;  // float32 eps
    double W = d[1];
    double swx[3] = { d[2], d[3], d[4] };
    double swy[3] = { d[5], d[6], d[7] };
    double swyx[9];
    for (int i = 0; i < 9; ++i) swyx[i] = d[8 + i];
    if (nep) {  // weights += EPS everywhere, applied analytically
        double corr[15];
        for (int k = 0; k < 15; ++k)
            corr[k] = csm[0][k] + csm[1][k] + csm[2][k] + csm[3][k];
        W += EPSF * (double)N;
        for (int i = 0; i < 3; ++i) { swx[i] += EPSF * corr[i]; swy[i] += EPSF * corr[3 + i]; }
        for (int i = 0; i < 9; ++i) swyx[i] += EPSF * corr[6 + i];
    }

    double mx[3], my[3];
    for (int i = 0; i < 3; ++i) { mx[i] = swx[i] / W; my[i] = swy[i] / W; }
    double S[3][3];
    for (int o = 0; o < 3; ++o)
        for (int i = 0; i < 3; ++i)
            S[o][i] = swyx[o * 3 + i] / W - my[o] * mx[i];

    // Jacobi eigendecomposition of B = S^T S  ->  V, lam
    double Bm[3][3], V[3][3];
    for (int i = 0; i < 3; ++i)
        for (int j = 0; j < 3; ++j) {
            double acc = 0.0;
            for (int k = 0; k < 3; ++k) acc += S[k][i] * S[k][j];
            Bm[i][j] = acc;
            V[i][j] = (i == j) ? 1.0 : 0.0;
        }
    for (int sweep = 0; sweep < 30; ++sweep) {
        double off2 = Bm[0][1]*Bm[0][1] + Bm[0][2]*Bm[0][2] + Bm[1][2]*Bm[1][2];
        double diag2 = Bm[0][0]*Bm[0][0] + Bm[1][1]*Bm[1][1] + Bm[2][2]*Bm[2][2];
        if (off2 <= diag2 * 1e-32 + 1e-300) break;
        for (int pair = 0; pair < 3; ++pair) {
            int p = (pair == 2) ? 1 : 0;
            int q = (pair == 0) ? 1 : 2;
            double apq = Bm[p][q];
            if (fabs(apq) < 1e-300) continue;
            double theta = (Bm[q][q] - Bm[p][p]) / (2.0 * apq);
            double tt = ((theta >= 0.0) ? 1.0 : -1.0) / (fabs(theta) + sqrt(1.0 + theta * theta));
            double c = 1.0 / sqrt(1.0 + tt * tt);
            double sn = tt * c;
            for (int k = 0; k < 3; ++k) {
                double bkp = Bm[k][p], bkq = Bm[k][q];
                Bm[k][p] = c * bkp - sn * bkq;
                Bm[k][q] = sn * bkp + c * bkq;
            }
            for (int k = 0; k < 3; ++k) {
                double bpk = Bm[p][k], bqk = Bm[q][k];
                Bm[p][k] = c * bpk - sn * bqk;
                Bm[q][k] = sn * bpk + c * bqk;
            }
            for (int k = 0; k < 3; ++k) {
                double vkp = V[k][p], vkq = V[k][q];
                V[k][p] = c * vkp - sn * vkq;
                V[k][q] = sn * vkp + c * vkq;
            }
        }
    }
    double lam[3] = { Bm[0][0], Bm[1][1], Bm[2][2] };
    for (int i = 0; i < 2; ++i)
        for (int j = i + 1; j < 3; ++j)
            if (lam[j] > lam[i]) {
                double tl = lam[i]; lam[i] = lam[j]; lam[j] = tl;
                for (int k = 0; k < 3; ++k) { double tv = V[k][i]; V[k][i] = V[k][j]; V[k][j] = tv; }
            }
    double sig[3];
    for (int i = 0; i < 3; ++i) sig[i] = sqrt(fmax(lam[i], 0.0));

    double U[3][3];
    for (int i = 0; i < 3; ++i) {
        double u0 = S[0][0]*V[0][i] + S[0][1]*V[1][i] + S[0][2]*V[2][i];
        double u1 = S[1][0]*V[0][i] + S[1][1]*V[1][i] + S[1][2]*V[2][i];
        double u2 = S[2][0]*V[0][i] + S[2][1]*V[1][i] + S[2][2]*V[2][i];
        double nrm = sqrt(u0*u0 + u1*u1 + u2*u2);
        if (nrm > 1e-150) {
            U[0][i] = u0 / nrm; U[1][i] = u1 / nrm; U[2][i] = u2 / nrm;
        } else if (i == 0) {
            U[0][0] = 1.0; U[1][0] = 0.0; U[2][0] = 0.0;
        } else if (i == 1) {
            double e0 = (fabs(U[0][0]) < 0.9) ? 1.0 : 0.0;
            double e1 = 1.0 - e0;
            double dp = e0 * U[0][0] + e1 * U[1][0];
            double v0 = e0 - dp * U[0][0], v1 = e1 - dp * U[1][0], v2 = -dp * U[2][0];
            double n2 = sqrt(v0*v0 + v1*v1 + v2*v2);
            U[0][1] = v0 / n2; U[1][1] = v1 / n2; U[2][1] = v2 / n2;
        } else {
            U[0][2] = U[1][0]*U[2][1] - U[2][0]*U[1][1];
            U[1][2] = U[2][0]*U[0][1] - U[0][0]*U[2][1];
            U[2][2] = U[0][0]*U[1][1] - U[1][0]*U[0][1];
        }
    }

    double tol = sig[0] * 3.0 * EPSF;
    int rank = (sig[0] > tol) + (sig[1] > tol) + (sig[2] > tol);
    double detS = det3(S);
    double det_mul = det3(U) * det3(V);
    double sign_full = (detS < 0.0) ? -1.0 : 1.0;
    double sign_def = (fabs(det_mul + 1.0) <= 1.00001e-5) ? -1.0 : 1.0;
    double s = (rank > 2) ? sign_full : sign_def;

    double R[3][3];
    for (int o = 0; o < 3; ++o)
        for (int i = 0; i < 3; ++i)
            R[o][i] = U[o][0]*V[i][0] + U[o][1]*V[i][1] + s * U[o][2]*V[i][2];
    double tv[3];
    for (int o = 0; o < 3; ++o)
        tv[o] = my[o] - (R[o][0]*mx[0] + R[o][1]*mx[1] + R[o][2]*mx[2]);

    for (int o = 0; o < 3; ++o) {
        out[o * 4 + 0] = (float)R[o][0];
        out[o * 4 + 1] = (float)R[o][1];
        out[o * 4 + 2] = (float)R[o][2];
        out[o * 4 + 3] = (float)tv[o];
    }
    out[12] = 0.0f; out[13] = 0.0f; out[14] = 0.0f; out[15] = 1.0f;
    out[16] = nep ? 1.0f : 0.0f;
}

extern "C" void kernel_launch(void* const* d_in, const int* in_sizes, int n_in,
                              void* d_out, int out_size, void* d_ws, size_t ws_size,
                              hipStream_t stream) {
    const float* c0 = (const float*)d_in[0];
    const float* c1 = (const float*)d_in[1];
    const float* w  = (const float*)d_in[2];
    float* out = (float*)d_out;
    int N = in_sizes[2];  // B=1: weights has N elements

    int ngrp = N >> 2;
    int blocks = (ngrp + 511) >> 9;     // 512 groups per block (2/thread/iter)
    if (blocks > 1024) blocks = 1024;   // N=4M -> 1024 blocks, 2 iterations
    if (blocks < 1) blocks = 1;

    float* acc32 = (float*)d_ws;   // 17 accs, each padded to its own 128B line
    unsigned* ticket = (unsigned*)((char*)d_ws + NACC * ACC_STRIDE * sizeof(float));

    hipMemsetAsync(d_ws, 0, NACC * ACC_STRIDE * sizeof(float) + sizeof(unsigned), stream);
    kabsch_fused<<<blocks, 256, 0, stream>>>(c0, c1, w, N, acc32, blocks, ticket, out);
}

// Round 12
// 148.962 us; speedup vs baseline: 1.0399x; 1.0399x over previous
//
#include <hip/hip_runtime.h>
#include <math.h>

#define NACC 32
#define ACC_STRIDE 32   // pad each f32 accumulator to its own 128B cache line
// acc layout: 0 cnt, 1 sw, 2-4 swx, 5-7 swy, 8-16 swyx[o*3+i],
//             17-19 sx, 20-22 sy, 23-31 syx[o*3+i]

typedef float f4 __attribute__((ext_vector_type(4)));

// Fence-free fused reduce+finalize — r9 config (best: 146.6us total,
// fused 44.4us) + ONE change: nontemporal (nt) loads on the hot streams.
// Rationale: 7 structural variants all pinned at 2.2-2.9 TB/s delivered
// read BW; FETCH_SIZE shows half the input served from L2/L3. nt policy
// changes the cache service path — last untried mechanism class.
// Standing constraints (verified):
//  - NO __threadfence (r4/r6: per-block wbl2 costs ~170us).
//  - Cross-block data via device-scope atomics only.
//  - No volatile-asm loads in the loop (r4: kills compiler pipelining).
//  - No cooperative launch (r5: never runs under graph capture).
//  - 17-acc lean loop regressed (r11: 53.4us) — keep 32 accs.

__device__ __forceinline__ void accum_point(float w, float x0, float x1, float x2,
                                            float y0, float y1, float y2, float* a) {
    a[0] += (w > 0.0f) ? 1.0f : 0.0f;
    a[1] += w;
    a[2] = fmaf(w, x0, a[2]); a[3] = fmaf(w, x1, a[3]); a[4] = fmaf(w, x2, a[4]);
    float wy0 = w * y0, wy1 = w * y1, wy2 = w * y2;
    a[5] += wy0; a[6] += wy1; a[7] += wy2;
    a[8]  = fmaf(wy0, x0, a[8]);  a[9]  = fmaf(wy0, x1, a[9]);  a[10] = fmaf(wy0, x2, a[10]);
    a[11] = fmaf(wy1, x0, a[11]); a[12] = fmaf(wy1, x1, a[12]); a[13] = fmaf(wy1, x2, a[13]);
    a[14] = fmaf(wy2, x0, a[14]); a[15] = fmaf(wy2, x1, a[15]); a[16] = fmaf(wy2, x2, a[16]);
    a[17] += x0; a[18] += x1; a[19] += x2;
    a[20] += y0; a[21] += y1; a[22] += y2;
    a[23] = fmaf(y0, x0, a[23]); a[24] = fmaf(y0, x1, a[24]); a[25] = fmaf(y0, x2, a[25]);
    a[26] = fmaf(y1, x0, a[26]); a[27] = fmaf(y1, x1, a[27]); a[28] = fmaf(y1, x2, a[28]);
    a[29] = fmaf(y2, x0, a[29]); a[30] = fmaf(y2, x1, a[30]); a[31] = fmaf(y2, x2, a[31]);
}

__device__ __forceinline__ double det3(const double m[3][3]) {
    return m[0][0] * (m[1][1] * m[2][2] - m[1][2] * m[2][1])
         - m[0][1] * (m[1][0] * m[2][2] - m[1][2] * m[2][0])
         + m[0][2] * (m[1][0] * m[2][1] - m[1][1] * m[2][0]);
}

__global__ __launch_bounds__(256, 1) void kabsch_fused(
    const float* __restrict__ c0, const float* __restrict__ c1,
    const float* __restrict__ w, int N, float* __restrict__ acc32, int nblocks,
    unsigned* __restrict__ ticket, float* __restrict__ out) {
    __shared__ float wred[4][NACC];

    float a[NACC];
    #pragma unroll
    for (int i = 0; i < NACC; ++i) a[i] = 0.0f;

    const int t = threadIdx.x;
    const int lane = t & 63, wave = t >> 6;
    const f4* __restrict__ A4 = (const f4*)c0;
    const f4* __restrict__ B4 = (const f4*)c1;
    const f4* __restrict__ W4 = (const f4*)w;

    // ---- software-pipelined hot loop (r9) with nontemporal loads ----
    const int ngrp = N >> 2;
    const int stride = gridDim.x << 8;   // gridDim.x * 256
    {
        int g = (blockIdx.x << 8) + t;
        if (g < ngrp) {
            const f4* pa = A4 + 3 * (size_t)g;
            const f4* pb = B4 + 3 * (size_t)g;
            f4 ca0 = __builtin_nontemporal_load(pa);
            f4 ca1 = __builtin_nontemporal_load(pa + 1);
            f4 ca2 = __builtin_nontemporal_load(pa + 2);
            f4 cb0 = __builtin_nontemporal_load(pb);
            f4 cb1 = __builtin_nontemporal_load(pb + 1);
            f4 cb2 = __builtin_nontemporal_load(pb + 2);
            f4 cw  = __builtin_nontemporal_load(W4 + g);
            for (int gn = g + stride; ; gn += stride) {
                const bool more = gn < ngrp;
                f4 na0, na1, na2, nb0, nb1, nb2, nw;
                if (more) {
                    const f4* qa = A4 + 3 * (size_t)gn;
                    const f4* qb = B4 + 3 * (size_t)gn;
                    na0 = __builtin_nontemporal_load(qa);
                    na1 = __builtin_nontemporal_load(qa + 1);
                    na2 = __builtin_nontemporal_load(qa + 2);
                    nb0 = __builtin_nontemporal_load(qb);
                    nb1 = __builtin_nontemporal_load(qb + 1);
                    nb2 = __builtin_nontemporal_load(qb + 2);
                    nw  = __builtin_nontemporal_load(W4 + gn);
                }
                accum_point(cw.x, ca0.x, ca0.y, ca0.z, cb0.x, cb0.y, cb0.z, a);
                accum_point(cw.y, ca0.w, ca1.x, ca1.y, cb0.w, cb1.x, cb1.y, a);
                accum_point(cw.z, ca1.z, ca1.w, ca2.x, cb1.z, cb1.w, cb2.x, a);
                accum_point(cw.w, ca2.y, ca2.z, ca2.w, cb2.y, cb2.z, cb2.w, a);
                if (!more) break;
                ca0 = na0; ca1 = na1; ca2 = na2;
                cb0 = nb0; cb1 = nb1; cb2 = nb2; cw = nw;
            }
        }
    }
    // tail points (N % 4) — never taken for N = 4M, correctness-general
    if (blockIdx.x == 0 && t == 0) {
        for (int i = (N >> 2) << 2; i < N; ++i)
            accum_point(w[i], c0[3*i], c0[3*i+1], c0[3*i+2],
                        c1[3*i], c1[3*i+1], c1[3*i+2], a);
    }

    // ---- multi-value butterfly wave reduction: 32 accs in 32 shuffles.
    // final mapping lane -> acc = bitrev5(lane&31). ----
    {
        int hi;
        hi = lane & 1;
        #pragma unroll
        for (int i = 0; i < 16; ++i) {
            float send = hi ? a[i] : a[i + 16];
            float recv = __shfl_xor(send, 1, 64);
            a[i] = (hi ? a[i + 16] : a[i]) + recv;
        }
        hi = lane & 2;
        #pragma unroll
        for (int i = 0; i < 8; ++i) {
            float send = hi ? a[i] : a[i + 8];
            float recv = __shfl_xor(send, 2, 64);
            a[i] = (hi ? a[i + 8] : a[i]) + recv;
        }
        hi = lane & 4;
        #pragma unroll
        for (int i = 0; i < 4; ++i) {
            float send = hi ? a[i] : a[i + 4];
            float recv = __shfl_xor(send, 4, 64);
            a[i] = (hi ? a[i + 4] : a[i]) + recv;
        }
        hi = lane & 8;
        #pragma unroll
        for (int i = 0; i < 2; ++i) {
            float send = hi ? a[i] : a[i + 2];
            float recv = __shfl_xor(send, 8, 64);
            a[i] = (hi ? a[i + 2] : a[i]) + recv;
        }
        hi = lane & 16;
        {
            float send = hi ? a[0] : a[1];
            float recv = __shfl_xor(send, 16, 64);
            a[0] = (hi ? a[1] : a[0]) + recv;
        }
        a[0] += __shfl_xor(a[0], 32, 64);
    }
    if (lane < 32) {
        int acc = ((lane & 1) << 4) | ((lane & 2) << 2) | (lane & 4)
                | ((lane & 8) >> 2) | ((lane & 16) >> 4);  // bitrev5
        wred[wave][acc] = a[0];
    }
    __syncthreads();

    // ---- publish via native device-scope f32 atomic add (no fence);
    // one accumulator per 128B line ----
    if (t < NACC) {
        float val = wred[0][t] + wred[1][t] + wred[2][t] + wred[3][t];
        float* p = acc32 + (t << 5);   // t * ACC_STRIDE
        asm volatile("global_atomic_add_f32 %0, %1, off"
                     :: "v"(p), "v"(val) : "memory");
    }
    asm volatile("s_waitcnt vmcnt(0)" ::: "memory");  // fadds performed
    __syncthreads();
    __shared__ unsigned amlast;
    if (t == 0) amlast = atomicAdd(ticket, 1u);       // relaxed, coherent
    __syncthreads();
    if (amlast != (unsigned)(nblocks - 1)) return;

    // ---- last-arriving block: read totals via atomic fadd(0, sc0) ----
    __shared__ float tot[NACC];
    if (t < NACC) {
        float* p = acc32 + (t << 5);
        float zero = 0.0f, old;
        asm volatile("global_atomic_add_f32 %0, %1, %2, off sc0"
                     : "=&v"(old) : "v"(p), "v"(zero) : "memory");
        asm volatile("s_waitcnt vmcnt(0)" ::: "memory");
        tot[t] = old;
    }
    __syncthreads();
    if (t != 0) return;

    double d[NACC];
    #pragma unroll
    for (int i = 0; i < NACC; ++i) d[i] = (double)tot[i];

    const double EPSF = (double)1.1920929e-7f;  // float32 eps
    double cnt = d[0];
    double W = d[1];
    double swx[3] = { d[2], d[3], d[4] };
    double swy[3] = { d[5], d[6], d[7] };
    double swyx[9];
    for (int i = 0; i < 9; ++i) swyx[i] = d[8 + i];
    bool nep = cnt < 3.0;
    if (nep) {  // weights += EPS everywhere, applied analytically
        W += EPSF * (double)N;
        for (int i = 0; i < 3; ++i) { swx[i] += EPSF * d[17 + i]; swy[i] += EPSF * d[20 + i]; }
        for (int i = 0; i < 9; ++i) swyx[i] += EPSF * d[23 + i];
    }

    double mx[3], my[3];
    for (int i = 0; i < 3; ++i) { mx[i] = swx[i] / W; my[i] = swy[i] / W; }
    double S[3][3];
    for (int o = 0; o < 3; ++o)
        for (int i = 0; i < 3; ++i)
            S[o][i] = swyx[o * 3 + i] / W - my[o] * mx[i];

    // Jacobi eigendecomposition of B = S^T S  ->  V, lam
    double Bm[3][3], V[3][3];
    for (int i = 0; i < 3; ++i)
        for (int j = 0; j < 3; ++j) {
            double acc = 0.0;
            for (int k = 0; k < 3; ++k) acc += S[k][i] * S[k][j];
            Bm[i][j] = acc;
            V[i][j] = (i == j) ? 1.0 : 0.0;
        }
    for (int sweep = 0; sweep < 30; ++sweep) {
        double off2 = Bm[0][1]*Bm[0][1] + Bm[0][2]*Bm[0][2] + Bm[1][2]*Bm[1][2];
        double diag2 = Bm[0][0]*Bm[0][0] + Bm[1][1]*Bm[1][1] + Bm[2][2]*Bm[2][2];
        if (off2 <= diag2 * 1e-32 + 1e-300) break;
        for (int pair = 0; pair < 3; ++pair) {
            int p = (pair == 2) ? 1 : 0;
            int q = (pair == 0) ? 1 : 2;
            double apq = Bm[p][q];
            if (fabs(apq) < 1e-300) continue;
            double theta = (Bm[q][q] - Bm[p][p]) / (2.0 * apq);
            double tt = ((theta >= 0.0) ? 1.0 : -1.0) / (fabs(theta) + sqrt(1.0 + theta * theta));
            double c = 1.0 / sqrt(1.0 + tt * tt);
            double sn = tt * c;
            for (int k = 0; k < 3; ++k) {
                double bkp = Bm[k][p], bkq = Bm[k][q];
                Bm[k][p] = c * bkp - sn * bkq;
                Bm[k][q] = sn * bkp + c * bkq;
            }
            for (int k = 0; k < 3; ++k) {
                double bpk = Bm[p][k], bqk = Bm[q][k];
                Bm[p][k] = c * bpk - sn * bqk;
                Bm[q][k] = sn * bpk + c * bqk;
            }
            for (int k = 0; k < 3; ++k) {
                double vkp = V[k][p], vkq = V[k][q];
                V[k][p] = c * vkp - sn * vkq;
                V[k][q] = sn * vkp + c * vkq;
            }
        }
    }
    double lam[3] = { Bm[0][0], Bm[1][1], Bm[2][2] };
    for (int i = 0; i < 2; ++i)
        for (int j = i + 1; j < 3; ++j)
            if (lam[j] > lam[i]) {
                double tl = lam[i]; lam[i] = lam[j]; lam[j] = tl;
                for (int k = 0; k < 3; ++k) { double tv = V[k][i]; V[k][i] = V[k][j]; V[k][j] = tv; }
            }
    double sig[3];
    for (int i = 0; i < 3; ++i) sig[i] = sqrt(fmax(lam[i], 0.0));

    double U[3][3];
    for (int i = 0; i < 3; ++i) {
        double u0 = S[0][0]*V[0][i] + S[0][1]*V[1][i] + S[0][2]*V[2][i];
        double u1 = S[1][0]*V[0][i] + S[1][1]*V[1][i] + S[1][2]*V[2][i];
        double u2 = S[2][0]*V[0][i] + S[2][1]*V[1][i] + S[2][2]*V[2][i];
        double nrm = sqrt(u0*u0 + u1*u1 + u2*u2);
        if (nrm > 1e-150) {
            U[0][i] = u0 / nrm; U[1][i] = u1 / nrm; U[2][i] = u2 / nrm;
        } else if (i == 0) {
            U[0][0] = 1.0; U[1][0] = 0.0; U[2][0] = 0.0;
        } else if (i == 1) {
            double e0 = (fabs(U[0][0]) < 0.9) ? 1.0 : 0.0;
            double e1 = 1.0 - e0;
            double dp = e0 * U[0][0] + e1 * U[1][0];
            double v0 = e0 - dp * U[0][0], v1 = e1 - dp * U[1][0], v2 = -dp * U[2][0];
            double n2 = sqrt(v0*v0 + v1*v1 + v2*v2);
            U[0][1] = v0 / n2; U[1][1] = v1 / n2; U[2][1] = v2 / n2;
        } else {
            U[0][2] = U[1][0]*U[2][1] - U[2][0]*U[1][1];
            U[1][2] = U[2][0]*U[0][1] - U[0][0]*U[2][1];
            U[2][2] = U[0][0]*U[1][1] - U[1][0]*U[0][1];
        }
    }

    double tol = sig[0] * 3.0 * EPSF;
    int rank = (sig[0] > tol) + (sig[1] > tol) + (sig[2] > tol);
    double detS = det3(S);
    double det_mul = det3(U) * det3(V);
    double sign_full = (detS < 0.0) ? -1.0 : 1.0;
    double sign_def = (fabs(det_mul + 1.0) <= 1.00001e-5) ? -1.0 : 1.0;
    double s = (rank > 2) ? sign_full : sign_def;

    double R[3][3];
    for (int o = 0; o < 3; ++o)
        for (int i = 0; i < 3; ++i)
            R[o][i] = U[o][0]*V[i][0] + U[o][1]*V[i][1] + s * U[o][2]*V[i][2];
    double tv[3];
    for (int o = 0; o < 3; ++o)
        tv[o] = my[o] - (R[o][0]*mx[0] + R[o][1]*mx[1] + R[o][2]*mx[2]);

    for (int o = 0; o < 3; ++o) {
        out[o * 4 + 0] = (float)R[o][0];
        out[o * 4 + 1] = (float)R[o][1];
        out[o * 4 + 2] = (float)R[o][2];
        out[o * 4 + 3] = (float)tv[o];
    }
    out[12] = 0.0f; out[13] = 0.0f; out[14] = 0.0f; out[15] = 1.0f;
    out[16] = nep ? 1.0f : 0.0f;
}

extern "C" void kernel_launch(void* const* d_in, const int* in_sizes, int n_in,
                              void* d_out, int out_size, void* d_ws, size_t ws_size,
                              hipStream_t stream) {
    const float* c0 = (const float*)d_in[0];
    const float* c1 = (const float*)d_in[1];
    const float* w  = (const float*)d_in[2];
    float* out = (float*)d_out;
    int N = in_sizes[2];  // B=1: weights has N elements

    int ngrp = N >> 2;
    int blocks = (ngrp + 255) >> 8;
    if (blocks > 1024) blocks = 1024;   // N=4M -> 1024 blocks, 4 groups/thread
    if (blocks < 1) blocks = 1;

    float* acc32 = (float*)d_ws;   // 32 accs, each padded to its own 128B line
    unsigned* ticket = (unsigned*)((char*)d_ws + NACC * ACC_STRIDE * sizeof(float));

    hipMemsetAsync(d_ws, 0, NACC * ACC_STRIDE * sizeof(float) + sizeof(unsigned), stream);
    kabsch_fused<<<blocks, 256, 0, stream>>>(c0, c1, w, N, acc32, blocks, ticket, out);
}